// Round 2
// baseline (178.465 us; speedup 1.0000x reference)
//
#include <hip/hip_runtime.h>

#define N_ROWS 8192
#define D_DIM  256
#define EPS    1e-6f
#define MARGIN 0.5f

typedef __bf16 bf16x8 __attribute__((ext_vector_type(8)));
typedef float  f32x4  __attribute__((ext_vector_type(4)));

// round-to-nearest-even fp32 -> bf16 (inputs are finite normals; no NaN path needed)
__device__ inline unsigned short f2bf(float f) {
    unsigned u = __float_as_uint(f);
    unsigned r = (u + 0x7FFFu + ((u >> 16) & 1u)) >> 16;
    return (unsigned short)r;
}

// Prep: fp32 X[8192][256] -> bf16 swizzled Xs (MFMA fragment order) + fp32 row sums.
// Swizzle: element (row, k) -> ((rb*8 + kb)*64 + lane)*8 + (k&7)
//   rb = row>>4, kb = k>>5, lane = ((k>>3)&3)*16 + (row&15)
// so a wave fragment load for (rb, kb) is lane-contiguous 16B each = coalesced 1KB.
__global__ void prep_kernel(const float* __restrict__ X,
                            unsigned short* __restrict__ Xs,
                            float* __restrict__ sq, float* __restrict__ s) {
    __shared__ float lsq[256], ls[256];
    int t = threadIdx.x;
    int rb = blockIdx.x;           // 16-row block
    int lr = t >> 4;               // local row 0..15
    int row = rb * 16 + lr;
    int c0 = (t & 15) * 16;        // 16-col segment
    const float* xp = X + (size_t)row * D_DIM + c0;

    float x[16];
    for (int i = 0; i < 4; i++) {
        float4 v = ((const float4*)xp)[i];
        x[4*i+0] = v.x; x[4*i+1] = v.y; x[4*i+2] = v.z; x[4*i+3] = v.w;
    }
    float psq = 0.f, ps = 0.f;
    for (int i = 0; i < 16; i++) { psq += x[i] * x[i]; ps += x[i]; }
    lsq[t] = psq; ls[t] = ps;

    for (int h = 0; h < 2; h++) {
        int c  = c0 + h * 8;
        int kb = c >> 5;
        int qq = (c >> 3) & 3;
        int lane = qq * 16 + lr;
        size_t base = ((size_t)(rb * 8 + kb) * 64 + lane) * 8;
        union { unsigned short us[8]; uint4 u4; } pk;
        for (int j = 0; j < 8; j++) pk.us[j] = f2bf(x[h * 8 + j]);
        *(uint4*)(Xs + base) = pk.u4;
    }
    __syncthreads();
    if (t < 16) {
        float aq = 0.f, as = 0.f;
        for (int i = 0; i < 16; i++) { aq += lsq[t * 16 + i]; as += ls[t * 16 + i]; }
        int orow = rb * 16 + t;
        sq[orow] = aq; s[orow] = as;
    }
}

// Fused gram + contrastive loss. Block = 256 threads = 4 waves (2x2),
// block tile 128x128, wave tile 64x64 (4x4 MFMA 16x16 accumulators).
// Upper-triangle blocks only; off-diagonal weighted 2x (eps-linear terms
// cancel pairwise: d2[i][j]+d2[j][i] == 2*(sq_i+sq_j-2g+d*eps^2); the
// residual 4*eps*(s_i-s_j) error is zero-mean ~1e-4/pair, negligible vs
// the 839.68 threshold).
__global__ __launch_bounds__(256)
void gram_loss_kernel(const unsigned short* __restrict__ Xs,
                      const float* __restrict__ sq, const float* __restrict__ s,
                      const int* __restrict__ tgt,
                      float* __restrict__ out) {
    int bi = blockIdx.x, bj = blockIdx.y;
    if (bj < bi) return;                       // symmetry: upper triangle only
    float weight = (bi == bj) ? 1.0f : 2.0f;

    int wave = threadIdx.x >> 6;
    int lane = threadIdx.x & 63;
    int wr = wave >> 1, wc = wave & 1;
    int rb0 = bi * 8 + wr * 4;                 // base 16-row block (4 of them)
    int cb0 = bj * 8 + wc * 4;                 // base 16-col block (4 of them)

    f32x4 acc[4][4];
    for (int r = 0; r < 4; r++)
        for (int c = 0; c < 4; c++)
            for (int e = 0; e < 4; e++) acc[r][c][e] = 0.0f;

    for (int kb = 0; kb < 8; kb++) {
        bf16x8 a[4], b[4];
        for (int r = 0; r < 4; r++) {
            size_t off = ((size_t)((rb0 + r) * 8 + kb) * 64 + lane) * 8;
            a[r] = *(const bf16x8*)(Xs + off);
        }
        for (int c = 0; c < 4; c++) {
            size_t off = ((size_t)((cb0 + c) * 8 + kb) * 64 + lane) * 8;
            b[c] = *(const bf16x8*)(Xs + off);
        }
        for (int r = 0; r < 4; r++)
            for (int c = 0; c < 4; c++)
                acc[r][c] = __builtin_amdgcn_mfma_f32_16x16x32_bf16(
                    a[r], b[c], acc[r][c], 0, 0, 0);
    }

    // Epilogue: C/D layout col = lane&15, row = (lane>>4)*4 + e  [m89-verified]
    int rquad = (lane >> 4) * 4;
    int lcol  = lane & 15;
    float sqc[4], scv[4];
    int tc[4];
    for (int c = 0; c < 4; c++) {
        int col = (cb0 + c) * 16 + lcol;
        sqc[c] = sq[col]; scv[c] = s[col]; tc[c] = tgt[col];
    }

    float partial = 0.0f;
    const float deps2 = (float)D_DIM * EPS * EPS;
    for (int r = 0; r < 4; r++) {
        int rowbase = (rb0 + r) * 16 + rquad;
        for (int e = 0; e < 4; e++) {
            int row = rowbase + e;
            float sqr = sq[row];
            float sr  = s[row];
            int tr = tgt[row];
            for (int c = 0; c < 4; c++) {
                float g  = acc[r][c][e];
                float d2 = sqr + sqc[c] - 2.0f * g
                         + 2.0f * EPS * (sr - scv[c]) + deps2;
                partial += (tr == tc[c]) ? d2 : fmaxf(MARGIN - d2, 0.0f);
            }
        }
    }

    partial *= weight;
    for (int off = 32; off > 0; off >>= 1)
        partial += __shfl_down(partial, off, 64);
    if (lane == 0)
        atomicAdd(out, partial * (1.0f / (float)N_ROWS));
}

extern "C" void kernel_launch(void* const* d_in, const int* in_sizes, int n_in,
                              void* d_out, int out_size, void* d_ws, size_t ws_size,
                              hipStream_t stream) {
    const float* X       = (const float*)d_in[0];
    const int* tgt       = (const int*)d_in[1];   // harness passes integer inputs as int32
    float* out           = (float*)d_out;

    unsigned short* Xs = (unsigned short*)d_ws;                       // 4 MB bf16 swizzled
    float* sq = (float*)((char*)d_ws + (size_t)N_ROWS * D_DIM * 2);   // 32 KB
    float* s  = sq + N_ROWS;                                          // 32 KB

    hipMemsetAsync(d_out, 0, sizeof(float), stream);
    prep_kernel<<<N_ROWS / 16, 256, 0, stream>>>(X, Xs, sq, s);
    gram_loss_kernel<<<dim3(64, 64), 256, 0, stream>>>(Xs, sq, s, tgt, out);
}

// Round 3
// 112.631 us; speedup vs baseline: 1.5845x; 1.5845x over previous
//
#include <hip/hip_runtime.h>

#define N_ROWS 8192
#define D_DIM  256
#define EPS    1e-6f
#define MARGIN 0.5f
#define NPART  4096   // 64*64 per-block partials

typedef __bf16 bf16x8 __attribute__((ext_vector_type(8)));
typedef float  f32x4  __attribute__((ext_vector_type(4)));

// round-to-nearest-even fp32 -> bf16
__device__ inline unsigned short f2bf(float f) {
    unsigned u = __float_as_uint(f);
    unsigned r = (u + 0x7FFFu + ((u >> 16) & 1u)) >> 16;
    return (unsigned short)r;
}

// Prep: fp32 X[8192][256] -> bf16 swizzled Xs (MFMA fragment order) + fp32 row sums.
// Swizzle: element (row, k) -> ((rb*8 + kb)*64 + lane)*8 + (k&7)
//   rb = row>>4, kb = k>>5, lane = ((k>>3)&3)*16 + (row&15)
__global__ void prep_kernel(const float* __restrict__ X,
                            unsigned short* __restrict__ Xs,
                            float* __restrict__ sq, float* __restrict__ s) {
    __shared__ float lsq[256], ls[256];
    int t = threadIdx.x;
    int rb = blockIdx.x;           // 16-row block
    int lr = t >> 4;               // local row 0..15
    int row = rb * 16 + lr;
    int c0 = (t & 15) * 16;        // 16-col segment
    const float* xp = X + (size_t)row * D_DIM + c0;

    float x[16];
    for (int i = 0; i < 4; i++) {
        float4 v = ((const float4*)xp)[i];
        x[4*i+0] = v.x; x[4*i+1] = v.y; x[4*i+2] = v.z; x[4*i+3] = v.w;
    }
    float psq = 0.f, ps = 0.f;
    for (int i = 0; i < 16; i++) { psq += x[i] * x[i]; ps += x[i]; }
    lsq[t] = psq; ls[t] = ps;

    for (int h = 0; h < 2; h++) {
        int c  = c0 + h * 8;
        int kb = c >> 5;
        int qq = (c >> 3) & 3;
        int lane = qq * 16 + lr;
        size_t base = ((size_t)(rb * 8 + kb) * 64 + lane) * 8;
        union { unsigned short us[8]; uint4 u4; } pk;
        for (int j = 0; j < 8; j++) pk.us[j] = f2bf(x[h * 8 + j]);
        *(uint4*)(Xs + base) = pk.u4;
    }
    __syncthreads();
    if (t < 16) {
        float aq = 0.f, as = 0.f;
        for (int i = 0; i < 16; i++) { aq += lsq[t * 16 + i]; as += ls[t * 16 + i]; }
        int orow = rb * 16 + t;
        sq[orow] = aq; s[orow] = as;
    }
}

// Fused gram + contrastive loss. Block = 256 threads = 4 waves (2x2),
// block tile 128x128, wave tile 64x64 (4x4 MFMA 16x16 accumulators).
// Upper-triangle blocks only; off-diagonal weighted 2x (loss matrix symmetric
// up to eps-linear terms that cancel pairwise; residual is ~1e-4 total).
// NO global atomics: per-block partial -> ws (same-address atomicAdd drain
// was the entire 100us stall in R2: 8320 serialized RMWs ~ 34cyc each).
__global__ __launch_bounds__(256)
void gram_loss_kernel(const unsigned short* __restrict__ Xs,
                      const float* __restrict__ sq, const float* __restrict__ s,
                      const int* __restrict__ tgt,
                      float* __restrict__ partials) {
    __shared__ float wsum[4];
    int bi = blockIdx.x, bj = blockIdx.y;
    int bid = bj * 64 + bi;
    if (bj < bi) {                             // symmetry: dead block, zero its slot
        if (threadIdx.x == 0) partials[bid] = 0.0f;
        return;
    }
    float weight = (bi == bj) ? 1.0f : 2.0f;

    int wave = threadIdx.x >> 6;
    int lane = threadIdx.x & 63;
    int wr = wave >> 1, wc = wave & 1;
    int rb0 = bi * 8 + wr * 4;                 // base 16-row block (4 of them)
    int cb0 = bj * 8 + wc * 4;                 // base 16-col block (4 of them)

    f32x4 acc[4][4];
    for (int r = 0; r < 4; r++)
        for (int c = 0; c < 4; c++)
            for (int e = 0; e < 4; e++) acc[r][c][e] = 0.0f;

    for (int kb = 0; kb < 8; kb++) {
        bf16x8 a[4], b[4];
        for (int r = 0; r < 4; r++) {
            size_t off = ((size_t)((rb0 + r) * 8 + kb) * 64 + lane) * 8;
            a[r] = *(const bf16x8*)(Xs + off);
        }
        for (int c = 0; c < 4; c++) {
            size_t off = ((size_t)((cb0 + c) * 8 + kb) * 64 + lane) * 8;
            b[c] = *(const bf16x8*)(Xs + off);
        }
        for (int r = 0; r < 4; r++)
            for (int c = 0; c < 4; c++)
                acc[r][c] = __builtin_amdgcn_mfma_f32_16x16x32_bf16(
                    a[r], b[c], acc[r][c], 0, 0, 0);
    }

    // Epilogue: C/D layout col = lane&15, row = (lane>>4)*4 + e  [m89-verified]
    int rquad = (lane >> 4) * 4;
    int lcol  = lane & 15;
    float sqc[4], scv[4];
    int tc[4];
    for (int c = 0; c < 4; c++) {
        int col = (cb0 + c) * 16 + lcol;
        sqc[c] = sq[col]; scv[c] = s[col]; tc[c] = tgt[col];
    }

    float partial = 0.0f;
    const float deps2 = (float)D_DIM * EPS * EPS;
    for (int r = 0; r < 4; r++) {
        int rowbase = (rb0 + r) * 16 + rquad;
        for (int e = 0; e < 4; e++) {
            int row = rowbase + e;
            float sqr = sq[row];
            float sr  = s[row];
            int tr = tgt[row];
            for (int c = 0; c < 4; c++) {
                float g  = acc[r][c][e];
                float d2 = sqr + sqc[c] - 2.0f * g
                         + 2.0f * EPS * (sr - scv[c]) + deps2;
                partial += (tr == tc[c]) ? d2 : fmaxf(MARGIN - d2, 0.0f);
            }
        }
    }

    partial *= weight;
    for (int off = 32; off > 0; off >>= 1)
        partial += __shfl_down(partial, off, 64);
    if (lane == 0) wsum[wave] = partial;
    __syncthreads();
    if (threadIdx.x == 0)
        partials[bid] = wsum[0] + wsum[1] + wsum[2] + wsum[3];
}

// Final reduce: 4096 partials -> out[0] (also applies 1/N scale).
__global__ __launch_bounds__(256)
void reduce_kernel(const float* __restrict__ partials, float* __restrict__ out) {
    __shared__ float wsum[4];
    int t = threadIdx.x;
    float v = 0.0f;
    for (int i = 0; i < NPART / 256; i++) v += partials[t + i * 256];
    for (int off = 32; off > 0; off >>= 1)
        v += __shfl_down(v, off, 64);
    int wave = t >> 6, lane = t & 63;
    if (lane == 0) wsum[wave] = v;
    __syncthreads();
    if (t == 0)
        out[0] = (wsum[0] + wsum[1] + wsum[2] + wsum[3]) * (1.0f / (float)N_ROWS);
}

extern "C" void kernel_launch(void* const* d_in, const int* in_sizes, int n_in,
                              void* d_out, int out_size, void* d_ws, size_t ws_size,
                              hipStream_t stream) {
    const float* X       = (const float*)d_in[0];
    const int* tgt       = (const int*)d_in[1];   // harness passes integer inputs as int32
    float* out           = (float*)d_out;

    unsigned short* Xs = (unsigned short*)d_ws;                       // 4 MB bf16 swizzled
    float* sq = (float*)((char*)d_ws + (size_t)N_ROWS * D_DIM * 2);   // 32 KB
    float* s  = sq + N_ROWS;                                          // 32 KB
    float* partials = s + N_ROWS;                                     // 16 KB

    prep_kernel<<<N_ROWS / 16, 256, 0, stream>>>(X, Xs, sq, s);
    gram_loss_kernel<<<dim3(64, 64), 256, 0, stream>>>(Xs, sq, s, tgt, partials);
    reduce_kernel<<<1, 256, 0, stream>>>(partials, out);
}

// Round 4
// 87.931 us; speedup vs baseline: 2.0296x; 1.2809x over previous
//
#include <hip/hip_runtime.h>

#define N_ROWS 8192
#define D_DIM  256
#define EPS    1e-6f
#define MARGIN 0.5f
#define NBLK   64                    // 8192 / 128 tiles per dim
#define NTRI   (NBLK * (NBLK + 1) / 2)   // 2080 upper-triangle blocks

typedef __bf16 bf16x8 __attribute__((ext_vector_type(8)));
typedef float  f32x4  __attribute__((ext_vector_type(4)));

// round-to-nearest-even fp32 -> bf16
__device__ inline unsigned short f2bf(float f) {
    unsigned u = __float_as_uint(f);
    return (unsigned short)((u + 0x7FFFu + ((u >> 16) & 1u)) >> 16);
}

// async global->LDS, 16B per lane. dst is the chunk base (lane 0's slot);
// HW writes wave-uniform base + lane*16 (m104/m108). src is per-lane.
__device__ inline void gl_lds16(const void* g, void* l) {
    __builtin_amdgcn_global_load_lds(
        (const __attribute__((address_space(1))) unsigned int*)g,
        (__attribute__((address_space(3))) unsigned int*)l, 16, 0, 0);
}

// Prep: fp32 X[8192][256] -> bf16 swizzled Xs (MFMA fragment order) + row sums.
// element (row,k) -> ((rb*8 + kb)*64 + lane)*8 + (k&7)
//   rb=row>>4, kb=k>>5, lane=((k>>3)&3)*16 + (row&15)
// One fragment chunk (rb,kb) = 512 elems = 1KB, lane-contiguous.
__global__ void prep_kernel(const float* __restrict__ X,
                            unsigned short* __restrict__ Xs,
                            float* __restrict__ sq, float* __restrict__ s) {
    __shared__ float lsq[256], ls[256];
    int t = threadIdx.x;
    int rb = blockIdx.x;
    int lr = t >> 4;
    int row = rb * 16 + lr;
    int c0 = (t & 15) * 16;
    const float* xp = X + (size_t)row * D_DIM + c0;

    float x[16];
    for (int i = 0; i < 4; i++) {
        float4 v = ((const float4*)xp)[i];
        x[4*i+0] = v.x; x[4*i+1] = v.y; x[4*i+2] = v.z; x[4*i+3] = v.w;
    }
    float psq = 0.f, ps = 0.f;
    for (int i = 0; i < 16; i++) { psq += x[i] * x[i]; ps += x[i]; }
    lsq[t] = psq; ls[t] = ps;

    for (int h = 0; h < 2; h++) {
        int c  = c0 + h * 8;
        int kb = c >> 5;
        int qq = (c >> 3) & 3;
        int lane = qq * 16 + lr;
        size_t base = ((size_t)(rb * 8 + kb) * 64 + lane) * 8;
        const float* xh = x + h * 8;
        unsigned w0 = (unsigned)f2bf(xh[0]) | ((unsigned)f2bf(xh[1]) << 16);
        unsigned w1 = (unsigned)f2bf(xh[2]) | ((unsigned)f2bf(xh[3]) << 16);
        unsigned w2 = (unsigned)f2bf(xh[4]) | ((unsigned)f2bf(xh[5]) << 16);
        unsigned w3 = (unsigned)f2bf(xh[6]) | ((unsigned)f2bf(xh[7]) << 16);
        uint4 pk = make_uint4(w0, w1, w2, w3);
        *(uint4*)(Xs + base) = pk;
    }
    __syncthreads();
    if (t < 16) {
        float aq = 0.f, as = 0.f;
        for (int i = 0; i < 16; i++) { aq += lsq[t * 16 + i]; as += ls[t * 16 + i]; }
        int orow = rb * 16 + t;
        sq[orow] = aq; s[orow] = as;
    }
}

// Fused gram + contrastive loss, m97-style pipeline:
// triangular 1D grid (2080 blocks), 128x128 block tile, 4 waves (2x2),
// double-buffered LDS staging via global_load_lds (prefetch kb+1 during kb).
// Off-diagonal blocks weighted 2x (symmetry; eps-linear terms cancel pairwise).
__global__ __launch_bounds__(256)
void gram_loss_kernel(const unsigned short* __restrict__ Xs,
                      const float* __restrict__ sq, const float* __restrict__ s,
                      const int* __restrict__ tgt,
                      float* __restrict__ partials) {
    __shared__ __align__(16) unsigned short ldsA[2][4096];  // 8KB per buffer
    __shared__ __align__(16) unsigned short ldsB[2][4096];
    __shared__ float wsum[4];

    // decode linear block id -> (bi, bj), bj >= bi.  f(i) = i*64 - i*(i-1)/2
    int p = blockIdx.x;
    int bi = (int)(64.5f - sqrtf(64.5f * 64.5f - 2.0f * (float)p));
    if (bi < 0) bi = 0; if (bi > 63) bi = 63;
    while ((bi + 1) * 64 - ((bi + 1) * bi) / 2 <= p) bi++;
    while (bi * 64 - (bi * (bi - 1)) / 2 > p) bi--;
    int bj = bi + (p - (bi * 64 - (bi * (bi - 1)) / 2));
    float weight = (bi == bj) ? 1.0f : 2.0f;

    int wave = threadIdx.x >> 6;
    int lane = threadIdx.x & 63;
    int wr = wave >> 1, wc = wave & 1;

    // staging: 16 chunks of 1KB per kb (A:8, B:8); wave w stages A{2w,2w+1}, B{2w,2w+1}
    // src chunk c of A at byte offset ((bi*8+c)*8 + kb)*1024
    const char* xb = (const char*)Xs;
    const char* sA0 = xb + ((size_t)(bi * 8 + 2 * wave)     * 8) * 1024 + (size_t)lane * 16;
    const char* sA1 = xb + ((size_t)(bi * 8 + 2 * wave + 1) * 8) * 1024 + (size_t)lane * 16;
    const char* sB0 = xb + ((size_t)(bj * 8 + 2 * wave)     * 8) * 1024 + (size_t)lane * 16;
    const char* sB1 = xb + ((size_t)(bj * 8 + 2 * wave + 1) * 8) * 1024 + (size_t)lane * 16;
    unsigned short* dA0 = &ldsA[0][(2 * wave)     * 512];
    unsigned short* dA1 = &ldsA[0][(2 * wave + 1) * 512];
    unsigned short* dB0 = &ldsB[0][(2 * wave)     * 512];
    unsigned short* dB1 = &ldsB[0][(2 * wave + 1) * 512];

    f32x4 acc[4][4];
    for (int r = 0; r < 4; r++)
        for (int c = 0; c < 4; c++)
            for (int e = 0; e < 4; e++) acc[r][c][e] = 0.0f;

    // stage kb=0 into buffer 0
    gl_lds16(sA0, dA0); gl_lds16(sA1, dA1);
    gl_lds16(sB0, dB0); gl_lds16(sB1, dB1);
    __syncthreads();   // drains vmcnt (compiler emits waitcnt before barrier)

    const unsigned short* fA = &ldsA[0][(wr * 4) * 512] + lane * 8;
    const unsigned short* fB = &ldsB[0][(wc * 4) * 512] + lane * 8;

    for (int kb = 0; kb < 8; kb++) {
        int cur = kb & 1, nxt = cur ^ 1;
        if (kb < 7) {   // prefetch next kb into the other buffer (async)
            size_t ko = (size_t)(kb + 1) * 1024;
            size_t bo = (size_t)nxt * 8192;   // byte offset of buffer
            gl_lds16(sA0 + ko, (char*)dA0 + bo);
            gl_lds16(sA1 + ko, (char*)dA1 + bo);
            gl_lds16(sB0 + ko, (char*)dB0 + bo);
            gl_lds16(sB1 + ko, (char*)dB1 + bo);
        }
        const unsigned short* a_p = fA + (size_t)cur * 4096;
        const unsigned short* b_p = fB + (size_t)cur * 4096;
        bf16x8 a[4], b[4];
        for (int r = 0; r < 4; r++) a[r] = *(const bf16x8*)(a_p + r * 512);
        for (int c = 0; c < 4; c++) b[c] = *(const bf16x8*)(b_p + c * 512);
        for (int r = 0; r < 4; r++)
            for (int c = 0; c < 4; c++)
                acc[r][c] = __builtin_amdgcn_mfma_f32_16x16x32_bf16(
                    a[r], b[c], acc[r][c], 0, 0, 0);
        __syncthreads();   // staging of kb+1 complete; cur buffer free
    }

    // Epilogue: C/D layout col = lane&15, row = (lane>>4)*4 + e  [m89-verified]
    int rb0 = bi * 8 + wr * 4;
    int cb0 = bj * 8 + wc * 4;
    int rquad = (lane >> 4) * 4;
    int lcol  = lane & 15;
    float sqc[4], scv[4];
    int tc[4];
    for (int c = 0; c < 4; c++) {
        int col = (cb0 + c) * 16 + lcol;
        sqc[c] = sq[col]; scv[c] = s[col]; tc[c] = tgt[col];
    }

    float partial = 0.0f;
    const float deps2 = (float)D_DIM * EPS * EPS;
    for (int r = 0; r < 4; r++) {
        int rowbase = (rb0 + r) * 16 + rquad;
        for (int e = 0; e < 4; e++) {
            int row = rowbase + e;
            float sqr = sq[row];
            float sr  = s[row];
            int tr = tgt[row];
            for (int c = 0; c < 4; c++) {
                float g  = acc[r][c][e];
                float d2 = sqr + sqc[c] - 2.0f * g
                         + 2.0f * EPS * (sr - scv[c]) + deps2;
                partial += (tr == tc[c]) ? d2 : fmaxf(MARGIN - d2, 0.0f);
            }
        }
    }

    partial *= weight;
    for (int off = 32; off > 0; off >>= 1)
        partial += __shfl_down(partial, off, 64);
    if (lane == 0) wsum[wave] = partial;
    __syncthreads();
    if (threadIdx.x == 0)
        partials[p] = wsum[0] + wsum[1] + wsum[2] + wsum[3];
}

// Final reduce: NTRI partials -> out[0] with 1/N scale.
__global__ __launch_bounds__(256)
void reduce_kernel(const float* __restrict__ partials, float* __restrict__ out) {
    __shared__ float wsum[4];
    int t = threadIdx.x;
    float v = 0.0f;
    for (int i = t; i < NTRI; i += 256) v += partials[i];
    for (int off = 32; off > 0; off >>= 1)
        v += __shfl_down(v, off, 64);
    int wave = t >> 6, lane = t & 63;
    if (lane == 0) wsum[wave] = v;
    __syncthreads();
    if (t == 0)
        out[0] = (wsum[0] + wsum[1] + wsum[2] + wsum[3]) * (1.0f / (float)N_ROWS);
}

extern "C" void kernel_launch(void* const* d_in, const int* in_sizes, int n_in,
                              void* d_out, int out_size, void* d_ws, size_t ws_size,
                              hipStream_t stream) {
    const float* X  = (const float*)d_in[0];
    const int* tgt  = (const int*)d_in[1];   // harness passes integer inputs as int32
    float* out      = (float*)d_out;

    unsigned short* Xs = (unsigned short*)d_ws;                       // 4 MB bf16 swizzled
    float* sq = (float*)((char*)d_ws + (size_t)N_ROWS * D_DIM * 2);   // 32 KB
    float* s  = sq + N_ROWS;                                          // 32 KB
    float* partials = s + N_ROWS;                                     // ~8 KB

    prep_kernel<<<N_ROWS / 16, 256, 0, stream>>>(X, Xs, sq, s);
    gram_loss_kernel<<<NTRI, 256, 0, stream>>>(Xs, sq, s, tgt, partials);
    reduce_kernel<<<1, 256, 0, stream>>>(partials, out);
}